// Round 14
// baseline (231.322 us; speedup 1.0000x reference)
//
#include <hip/hip_runtime.h>
#include <stdint.h>

#define D_MODEL 1024
#define NHEAD 16
#define DKH 64
#define BATCH 4
#define SEQ 2048
#define M_ROWS (BATCH*SEQ)   // 8192
#define NBH (BATCH*NHEAD)    // 64

typedef float f32x4 __attribute__((ext_vector_type(4)));
typedef float f32x16 __attribute__((ext_vector_type(16)));
typedef __bf16 bf16x8 __attribute__((ext_vector_type(8)));
typedef short short4v __attribute__((ext_vector_type(4)));
typedef unsigned short ushort4v __attribute__((ext_vector_type(4)));
typedef unsigned short ushort8v __attribute__((ext_vector_type(8)));
typedef int int2v __attribute__((ext_vector_type(2)));
typedef int int4v __attribute__((ext_vector_type(4)));

__device__ __forceinline__ unsigned short f2bf(float x) {
    __bf16 b = (__bf16)x;                      // hardware v_cvt (RNE)
    return __builtin_bit_cast(unsigned short, b);
}
__device__ __forceinline__ unsigned int packbf2(float lo, float hi) {
    return (unsigned int)f2bf(lo) | ((unsigned int)f2bf(hi) << 16);
}

#define GLL(gsrc, ldst) \
    __builtin_amdgcn_global_load_lds((const __attribute__((address_space(1))) void*)(gsrc), \
                                     (__attribute__((address_space(3))) void*)(ldst), 16, 0, 0)

// ---------------------------------------------------------------------------
// Fragment-order layouts:
//   GEMM A-frag tile (256x64): [mtile][kt][half][mfrag(8)][kk(2)][lane][e8]
//   GEMM B-frag tile (128x64): [ntile][kt][nfrag(8)][kk(2)][lane][e8]
//   attn K tile  (64kv x 64d): [t32(2)][ds(4)][hi*32+row31][e8]   (B-frag of QK^T)
//   attn V tile  (64kv x 64d): [vt(2)][s(4)][hi*32+d31][e8]       (A-frag of PV x16)
//     elem = V[kv = s*16 + hi*8 + e][d = vt*32 + d31]
// ---------------------------------------------------------------------------

__device__ __forceinline__ void cvt8store(const float* __restrict__ src,
                                          unsigned short* __restrict__ dst) {
    float4 v0 = *(const float4*)(src);
    float4 v1 = *(const float4*)(src + 4);
    ushort8v o;
    o[0] = f2bf(v0.x); o[1] = f2bf(v0.y); o[2] = f2bf(v0.z); o[3] = f2bf(v0.w);
    o[4] = f2bf(v1.x); o[5] = f2bf(v1.y); o[6] = f2bf(v1.z); o[7] = f2bf(v1.w);
    *(ushort8v*)dst = o;
}

// ---------------------------------------------------------------------------
// Kernel 1: fp32 -> bf16 fragment-order packing
// ---------------------------------------------------------------------------
__global__ __launch_bounds__(256) void k_convert(
    const float* __restrict__ z,  const float* __restrict__ wq,
    const float* __restrict__ wk, const float* __restrict__ wv,
    const float* __restrict__ wo,
    const float* __restrict__ bq, const float* __restrict__ bk,
    const float* __restrict__ bv,
    unsigned short* __restrict__ zf, unsigned short* __restrict__ wqkvf,
    unsigned short* __restrict__ wobf, float* __restrict__ biasf)
{
    int i = blockIdx.x * 256 + threadIdx.x;   // 0 .. 2097151
    if (i < 1048576) {              // zf: 8192x1024 / 8
        int lane = i & 63, rest = i >> 6;
        int kk = rest & 1, mfrag = (rest >> 1) & 7, half = (rest >> 4) & 1;
        int kt = (rest >> 5) & 15, mtile = rest >> 9;
        int row = mtile * 256 + half * 128 + mfrag * 16 + (lane & 15);
        int k = kt * 64 + kk * 32 + (lane >> 4) * 8;
        cvt8store(z + (size_t)row * 1024 + k, zf + (size_t)i * 8);
    }
    int i2 = i - 1048576;
    if (i2 >= 0 && i2 < 393216) {   // wqkvf: 3072x1024 / 8
        int lane = i2 & 63, rest = i2 >> 6;
        int kk = rest & 1, nfrag = (rest >> 1) & 7;
        int kt = (rest >> 4) & 15, ntile = rest >> 8;
        int n = ntile * 128 + nfrag * 16 + (lane & 15);
        int k = kt * 64 + kk * 32 + (lane >> 4) * 8;
        const float* W = (n < 1024) ? wq : ((n < 2048) ? wk : wv);
        cvt8store(W + (size_t)(n & 1023) * 1024 + k, wqkvf + (size_t)i2 * 8);
    }
    int i3 = i2 - 393216;
    if (i3 >= 0 && i3 < 131072) {   // wobf: 1024x1024 / 8
        int lane = i3 & 63, rest = i3 >> 6;
        int kk = rest & 1, nfrag = (rest >> 1) & 7;
        int kt = (rest >> 4) & 15, ntile = rest >> 8;
        int n = ntile * 128 + nfrag * 16 + (lane & 15);
        int k = kt * 64 + kk * 32 + (lane >> 4) * 8;
        cvt8store(wo + (size_t)n * 1024 + k, wobf + (size_t)i3 * 8);
    }
    if (i < 1024) {
        biasf[i]        = bq[i];
        biasf[1024 + i] = bk[i];
        biasf[2048 + i] = bv[i];
    }
}

// ---------------------------------------------------------------------------
// Shared GEMM machinery (R10/R11): 256x128 tile, BK=64, 8 waves, 3-buffer
// rotation, counted vmcnt(6), fragment-linear LDS.
// ---------------------------------------------------------------------------
__device__ __forceinline__ void g_stage(const unsigned short* __restrict__ as_,
                                        const unsigned short* __restrict__ bs_,
                                        unsigned short* la, unsigned short* lb,
                                        int wid, int lane)
{
#pragma unroll
    for (int g = 0; g < 4; ++g)
        GLL(as_ + (wid + 8 * g) * 512 + lane * 8, la + (wid + 8 * g) * 512);
#pragma unroll
    for (int g = 0; g < 2; ++g)
        GLL(bs_ + (wid + 8 * g) * 512 + lane * 8, lb + (wid + 8 * g) * 512);
}

#define GEMM_KLOOP(Abase, Bbase)                                                      \
    g_stage(Abase, Bbase, &ldsA[0][0], &ldsB[0][0], wid, lane);                       \
    g_stage(Abase + 16384, Bbase + 8192, &ldsA[1][0], &ldsB[1][0], wid, lane);        \
    asm volatile("s_waitcnt vmcnt(6)" ::: "memory");                                  \
    __builtin_amdgcn_s_barrier();                                                     \
    for (int t = 0; t < 16; ++t) {                                                    \
        int buf = t % 3;                                                              \
        if (t + 2 < 16)                                                               \
            g_stage(Abase + (size_t)(t + 2) * 16384, Bbase + (size_t)(t + 2) * 8192,  \
                    &ldsA[(t + 2) % 3][0], &ldsB[(t + 2) % 3][0], wid, lane);         \
        const unsigned short* A = &ldsA[buf][0];                                      \
        const unsigned short* B = &ldsB[buf][0];                                      \
        bf16x8 b00 = *(const bf16x8*)(B + ((wn * 2 + 0) * 2 + 0) * 512 + lane * 8);   \
        bf16x8 b01 = *(const bf16x8*)(B + ((wn * 2 + 0) * 2 + 1) * 512 + lane * 8);   \
        bf16x8 b10 = *(const bf16x8*)(B + ((wn * 2 + 1) * 2 + 0) * 512 + lane * 8);   \
        bf16x8 b11 = *(const bf16x8*)(B + ((wn * 2 + 1) * 2 + 1) * 512 + lane * 8);   \
        _Pragma("unroll")                                                             \
        for (int ii = 0; ii < 8; ++ii) {                                              \
            bf16x8 a0 = *(const bf16x8*)(A + ((wm * 8 + ii) * 2 + 0) * 512 + lane * 8); \
            bf16x8 a1 = *(const bf16x8*)(A + ((wm * 8 + ii) * 2 + 1) * 512 + lane * 8); \
            acc[ii][0] = __builtin_amdgcn_mfma_f32_16x16x32_bf16(a0, b00, acc[ii][0], 0, 0, 0); \
            acc[ii][0] = __builtin_amdgcn_mfma_f32_16x16x32_bf16(a1, b01, acc[ii][0], 0, 0, 0); \
            acc[ii][1] = __builtin_amdgcn_mfma_f32_16x16x32_bf16(a0, b10, acc[ii][1], 0, 0, 0); \
            acc[ii][1] = __builtin_amdgcn_mfma_f32_16x16x32_bf16(a1, b11, acc[ii][1], 0, 0, 0); \
        }                                                                             \
        if (t < 14)       { asm volatile("s_waitcnt vmcnt(6)" ::: "memory"); }        \
        else if (t == 14) { asm volatile("s_waitcnt vmcnt(0)" ::: "memory"); }        \
        if (t < 15) { __builtin_amdgcn_sched_barrier(0); __builtin_amdgcn_s_barrier(); } \
    }

// ---------------------------------------------------------------------------
// Kernel 2: QKV projection (R11). Q row-major (pre-scaled log2e/8); K/V
// scattered into attention fragment order (V in the x16 A-frag layout).
// ---------------------------------------------------------------------------
__global__ __launch_bounds__(512) void k_gemm_qkv(
    const unsigned short* __restrict__ Af,   // zfrag
    const unsigned short* __restrict__ Bf,   // wqkvfrag
    const float* __restrict__ biasf,
    unsigned short* __restrict__ qb, unsigned short* __restrict__ kfrag,
    unsigned short* __restrict__ vfrag)
{
    __shared__ unsigned short ldsA[3][16384];
    __shared__ unsigned short ldsB[3][8192];

    int bid = blockIdx.x;
    int wg = (bid & 7) * 96 + (bid >> 3);    // 768 blocks, XCD-contiguous
    int tn = wg % 24, tm = wg / 24;
    int tid = threadIdx.x, wid = tid >> 6, lane = tid & 63;
    int wm = wid >> 2, wn = wid & 3;

    const unsigned short* Abase = Af + (size_t)tm * 16 * 16384;
    const unsigned short* Bbase = Bf + (size_t)tn * 16 * 8192;

    f32x4 acc[8][2] = {};
    GEMM_KLOOP(Abase, Bbase)

    const float QSC = 0.18033688011112042f;  // log2(e) / sqrt(64)
    int t3 = tn >> 3;  // 0=Q 1=K 2=V
#pragma unroll
    for (int j = 0; j < 2; ++j) {
        int col = tn * 128 + wn * 32 + j * 16 + (lane & 15);
        float bias = biasf[col];
        int d = col & 1023, h = d >> 6, dk = d & 63;
#pragma unroll
        for (int i = 0; i < 8; ++i) {
#pragma unroll
            for (int r = 0; r < 4; ++r) {
                int row = tm * 256 + wm * 128 + i * 16 + (lane >> 4) * 4 + r;
                float v = acc[i][j][r] + bias;
                if (t3 == 0) v *= QSC;
                unsigned short bv16 = f2bf(v);
                int b_ = row >> 11, s_ = row & 2047;
                int bh = b_ * NHEAD + h;
                if (t3 == 0) {
                    qb[((size_t)bh * SEQ + s_) * DKH + dk] = bv16;
                } else if (t3 == 1) {
                    int kvblk = s_ >> 6, r64 = s_ & 63;
                    int t32 = r64 >> 5, l5 = r64 & 31;
                    int ds = dk >> 4, hi2 = (dk >> 3) & 1, e = dk & 7;
                    kfrag[((size_t)(bh * 32 + kvblk)) * 4096 +
                          (t32 * 4 + ds) * 512 + (hi2 * 32 + l5) * 8 + e] = bv16;
                } else {
                    // V x16 A-frag: elem = V[kv = s*16+hi*8+e][d = vt*32+l5]
                    int kvblk = s_ >> 6, kv64 = s_ & 63;
                    int s16 = kv64 >> 4, hi2 = (kv64 >> 3) & 1, e = kv64 & 7;
                    int vt = dk >> 5, l5 = dk & 31;
                    vfrag[((size_t)(bh * 32 + kvblk)) * 4096 +
                          (vt * 4 + s16) * 512 + (hi2 * 32 + l5) * 8 + e] = bv16;
                }
            }
        }
    }
}

// ---------------------------------------------------------------------------
// Kernel 3: flash attention, barrier-free register streaming, 64 q-rows/wave.
//   L2 traffic halves vs R13: each wave's K/V fragment reads now feed TWO
//   32-q sub-tiles (2 GB -> 1 GB per dispatch). 4-wave blocks (256 thr),
//   512 blocks, XCD-grouped. No LDS, no barriers. V loaded after QK^T so
//   K registers die first.
// ---------------------------------------------------------------------------
__global__ __launch_bounds__(256) void k_attn(
    const unsigned short* __restrict__ qg,
    const unsigned short* __restrict__ kb,
    const unsigned short* __restrict__ vtb,
    unsigned short* __restrict__ ctxf)
{
    int bid = blockIdx.x;
    // XCD-grouped swizzle: the 8 q-tiles of a (b,h) land on the same XCD.
    int x = bid & 7, li = bid >> 3;
    int bh = x * 8 + (li >> 3);
    int qt = li & 7;

    int tid = threadIdx.x, wid = tid >> 6, lane = tid & 63;
    int lq = lane & 31, hi = lane >> 5;

    // Q B-frags for two 32-q sub-tiles: col q = lane&31, k(d) = ds*16+hi*8+e
    bf16x8 aq[2][4];
    {
        const unsigned short* qp = qg + ((size_t)bh * SEQ + qt * 256 + wid * 64 + lq) * DKH + hi * 8;
#pragma unroll
        for (int d = 0; d < 4; ++d) {
            aq[0][d] = *(const bf16x8*)(qp + d * 16);
            aq[1][d] = *(const bf16x8*)(qp + 32 * DKH + d * 16);
        }
    }

    float lsum[2] = { 0.f, 0.f };
    f32x16 oa[2][2] = {};   // [q-subtile][d-tile]; col q = lane&31

    const unsigned short* kp = kb  + (size_t)bh * 32 * 4096 + lane * 8;
    const unsigned short* vp = vtb + (size_t)bh * 32 * 4096 + lane * 8;

    for (int kt = 0; kt < 32; ++kt) {
        // ---- K fragments straight to registers (8x dwordx4, coalesced) ----
        bf16x8 kf[8];
#pragma unroll
        for (int f = 0; f < 8; ++f) kf[f] = *(const bf16x8*)(kp + f * 512);

        // ---- S^T = K Q^T for both q-subtiles (16x mfma_32x32x16) ----
        f32x16 st0[2] = {}, st1[2] = {};
        __builtin_amdgcn_s_setprio(1);
#pragma unroll
        for (int ds = 0; ds < 4; ++ds) {
#pragma unroll
            for (int qq = 0; qq < 2; ++qq) {
                st0[qq] = __builtin_amdgcn_mfma_f32_32x32x16_bf16(kf[ds],     aq[qq][ds], st0[qq], 0, 0, 0);
                st1[qq] = __builtin_amdgcn_mfma_f32_32x32x16_bf16(kf[4 + ds], aq[qq][ds], st1[qq], 0, 0, 0);
            }
        }
        __builtin_amdgcn_s_setprio(0);

        // ---- V fragments (K regs dead; latency hides under exp/pack) ----
        bf16x8 vf[8];
#pragma unroll
        for (int f = 0; f < 8; ++f) vf[f] = *(const bf16x8*)(vp + f * 512);

        // ---- P = 2^(S^T); pack; permlane into PV B-frags (per q-subtile) ----
        bf16x8 w[2][4];
#pragma unroll
        for (int qq = 0; qq < 2; ++qq) {
            unsigned int w16[16];
#pragma unroll
            for (int jj = 0; jj < 8; ++jj) {
                float p0 = __builtin_amdgcn_exp2f(st0[qq][2 * jj]);
                float p1 = __builtin_amdgcn_exp2f(st0[qq][2 * jj + 1]);
                lsum[qq] += p0 + p1;
                w16[jj] = packbf2(p0, p1);
            }
#pragma unroll
            for (int jj = 0; jj < 8; ++jj) {
                float p0 = __builtin_amdgcn_exp2f(st1[qq][2 * jj]);
                float p1 = __builtin_amdgcn_exp2f(st1[qq][2 * jj + 1]);
                lsum[qq] += p0 + p1;
                w16[8 + jj] = packbf2(p0, p1);
            }
#pragma unroll
            for (int s = 0; s < 4; ++s) {
                int base = (s >> 1) * 8 + (s & 1) * 4;
                int2v r1 = __builtin_amdgcn_permlane32_swap((int)w16[base + 0], (int)w16[base + 2], false, false);
                int2v r2 = __builtin_amdgcn_permlane32_swap((int)w16[base + 1], (int)w16[base + 3], false, false);
                int4v fr; fr[0] = r1[0]; fr[1] = r2[0]; fr[2] = r1[1]; fr[3] = r2[1];
                w[qq][s] = __builtin_bit_cast(bf16x8, fr);
            }
        }

        // ---- O^T += V^T @ P : 16x mfma_32x32x16 ----
        __builtin_amdgcn_s_setprio(1);
#pragma unroll
        for (int s = 0; s < 4; ++s) {
#pragma unroll
            for (int qq = 0; qq < 2; ++qq) {
                oa[qq][0] = __builtin_amdgcn_mfma_f32_32x32x16_bf16(vf[s],     w[qq][s], oa[qq][0], 0, 0, 0);
                oa[qq][1] = __builtin_amdgcn_mfma_f32_32x32x16_bf16(vf[4 + s], w[qq][s], oa[qq][1], 0, 0, 0);
            }
        }
        __builtin_amdgcn_s_setprio(0);

        kp += 4096; vp += 4096;
    }

    // ---- epilogue: scatter ctx into GEMM-A fragment order ----
    int b_ = bh >> 4, h = bh & 15;
#pragma unroll
    for (int qq = 0; qq < 2; ++qq) {
        float s = lsum[qq];
        s += __shfl_xor(s, 32);
        float inv = 1.0f / s;
        int s_ = qt * 256 + wid * 64 + qq * 32 + lq;
        int row = b_ * 2048 + s_;
        int mtile = row >> 8, half = (row >> 7) & 1, mfrag = (row >> 4) & 7, lrow = row & 15;
        unsigned short* cb = ctxf + (size_t)((mtile * 16 + h) * 2 + half) * 8192
                                  + mfrag * 1024 + lrow * 8 + 4 * hi;
#pragma unroll
        for (int m = 0; m < 4; ++m) {
            ushort4v s0, s1;
            s0[0] = f2bf(oa[qq][0][4 * m + 0] * inv); s0[1] = f2bf(oa[qq][0][4 * m + 1] * inv);
            s0[2] = f2bf(oa[qq][0][4 * m + 2] * inv); s0[3] = f2bf(oa[qq][0][4 * m + 3] * inv);
            *(ushort4v*)(cb + m * 128) = s0;                 // kk=0 (d<32)
            s1[0] = f2bf(oa[qq][1][4 * m + 0] * inv); s1[1] = f2bf(oa[qq][1][4 * m + 1] * inv);
            s1[2] = f2bf(oa[qq][1][4 * m + 2] * inv); s1[3] = f2bf(oa[qq][1][4 * m + 3] * inv);
            *(ushort4v*)(cb + 512 + m * 128) = s1;           // kk=1 (d>=32)
        }
    }
}

// ---------------------------------------------------------------------------
// Kernel 4: output projection (R10/R11)
// ---------------------------------------------------------------------------
__global__ __launch_bounds__(512) void k_gemm_out(
    const unsigned short* __restrict__ Af,   // ctxfrag
    const unsigned short* __restrict__ Bf,   // wobfrag
    const float* __restrict__ bo,
    float* __restrict__ out)
{
    __shared__ unsigned short ldsA[3][16384];
    __shared__ unsigned short ldsB[3][8192];

    int bid = blockIdx.x;
    int wg = (bid & 7) * 32 + (bid >> 3);    // 256 blocks
    int tn = wg % 8, tm = wg / 8;
    int tid = threadIdx.x, wid = tid >> 6, lane = tid & 63;
    int wm = wid >> 2, wn = wid & 3;

    const unsigned short* Abase = Af + (size_t)tm * 16 * 16384;
    const unsigned short* Bbase = Bf + (size_t)tn * 16 * 8192;

    f32x4 acc[8][2] = {};
    GEMM_KLOOP(Abase, Bbase)

#pragma unroll
    for (int j = 0; j < 2; ++j) {
        int col = tn * 128 + wn * 32 + j * 16 + (lane & 15);
        float bias = bo[col];
#pragma unroll
        for (int i = 0; i < 8; ++i) {
#pragma unroll
            for (int r = 0; r < 4; ++r) {
                int row = tm * 256 + wm * 128 + i * 16 + (lane >> 4) * 4 + r;
                out[(size_t)row * 1024 + col] = acc[i][j][r] + bias;
            }
        }
    }
}

// ---------------------------------------------------------------------------
extern "C" void kernel_launch(void* const* d_in, const int* in_sizes, int n_in,
                              void* d_out, int out_size, void* d_ws, size_t ws_size,
                              hipStream_t stream)
{
    const float* z  = (const float*)d_in[0];
    const float* Wq = (const float*)d_in[1];
    const float* bq = (const float*)d_in[2];
    const float* Wk = (const float*)d_in[3];
    const float* bk = (const float*)d_in[4];
    const float* Wv = (const float*)d_in[5];
    const float* bv = (const float*)d_in[6];
    const float* Wo = (const float*)d_in[7];
    const float* bo = (const float*)d_in[8];
    float* out = (float*)d_out;

    char* ws = (char*)d_ws;
    unsigned short* zf    = (unsigned short*)(ws);                        // 16 MB
    unsigned short* ctxf  = (unsigned short*)(ws);                        // 16 MB (reuse)
    unsigned short* wqkvf = (unsigned short*)(ws + (16ull << 20));        //  6 MB
    unsigned short* wobf  = (unsigned short*)(ws + (22ull << 20));        //  2 MB
    float*          biasf = (float*)(ws + (24ull << 20));                 // 12 KB
    unsigned short* qb    = (unsigned short*)(ws + (25ull << 20));        // 16 MB
    unsigned short* kfrag = (unsigned short*)(ws + (41ull << 20));        // 16 MB
    unsigned short* vfrag = (unsigned short*)(ws + (57ull << 20));        // 16 MB -> 73 MB total

    k_convert<<<8192, 256, 0, stream>>>(z, Wq, Wk, Wv, Wo, bq, bk, bv, zf, wqkvf, wobf, biasf);
    k_gemm_qkv<<<768, 512, 0, stream>>>(zf, wqkvf, biasf, qb, kfrag, vfrag);
    k_attn<<<NBH * 8, 256, 0, stream>>>(qb, kfrag, vfrag, ctxf);
    k_gemm_out<<<256, 512, 0, stream>>>(ctxf, wobf, bo, out);
}

// Round 15
// 221.245 us; speedup vs baseline: 1.0456x; 1.0456x over previous
//
#include <hip/hip_runtime.h>
#include <stdint.h>

#define D_MODEL 1024
#define NHEAD 16
#define DKH 64
#define BATCH 4
#define SEQ 2048
#define M_ROWS (BATCH*SEQ)   // 8192
#define NBH (BATCH*NHEAD)    // 64

typedef float f32x4 __attribute__((ext_vector_type(4)));
typedef float f32x16 __attribute__((ext_vector_type(16)));
typedef __bf16 bf16x8 __attribute__((ext_vector_type(8)));
typedef short short4v __attribute__((ext_vector_type(4)));
typedef unsigned short ushort4v __attribute__((ext_vector_type(4)));
typedef unsigned short ushort8v __attribute__((ext_vector_type(8)));
typedef int int2v __attribute__((ext_vector_type(2)));
typedef int int4v __attribute__((ext_vector_type(4)));

__device__ __forceinline__ unsigned short f2bf(float x) {
    __bf16 b = (__bf16)x;                      // hardware v_cvt (RNE)
    return __builtin_bit_cast(unsigned short, b);
}
__device__ __forceinline__ unsigned int packbf2(float lo, float hi) {
    return (unsigned int)f2bf(lo) | ((unsigned int)f2bf(hi) << 16);
}

#define GLL(gsrc, ldst) \
    __builtin_amdgcn_global_load_lds((const __attribute__((address_space(1))) void*)(gsrc), \
                                     (__attribute__((address_space(3))) void*)(ldst), 16, 0, 0)

// ---------------------------------------------------------------------------
// Fragment-order layouts:
//   GEMM A-frag tile (256x64): [mtile][kt][half][mfrag(8)][kk(2)][lane][e8]
//   GEMM B-frag tile (128x64): [ntile][kt][nfrag(8)][kk(2)][lane][e8]
//   attn K tile  (64kv x 64d): [t32(2)][ds(4)][hi*32+row31][e8]   (B-frag of QK^T)
//   attn V tile  (64kv x 64d): [vt(2)][s(4)][hi*32+d31][e8]       (A-frag of PV x16)
//     elem = V[kv = s*16 + hi*8 + e][d = vt*32 + d31]
// ---------------------------------------------------------------------------

__device__ __forceinline__ void cvt8store(const float* __restrict__ src,
                                          unsigned short* __restrict__ dst) {
    float4 v0 = *(const float4*)(src);
    float4 v1 = *(const float4*)(src + 4);
    ushort8v o;
    o[0] = f2bf(v0.x); o[1] = f2bf(v0.y); o[2] = f2bf(v0.z); o[3] = f2bf(v0.w);
    o[4] = f2bf(v1.x); o[5] = f2bf(v1.y); o[6] = f2bf(v1.z); o[7] = f2bf(v1.w);
    *(ushort8v*)dst = o;
}

// ---------------------------------------------------------------------------
// Kernel 1: fp32 -> bf16 fragment-order packing
// ---------------------------------------------------------------------------
__global__ __launch_bounds__(256) void k_convert(
    const float* __restrict__ z,  const float* __restrict__ wq,
    const float* __restrict__ wk, const float* __restrict__ wv,
    const float* __restrict__ wo,
    const float* __restrict__ bq, const float* __restrict__ bk,
    const float* __restrict__ bv,
    unsigned short* __restrict__ zf, unsigned short* __restrict__ wqkvf,
    unsigned short* __restrict__ wobf, float* __restrict__ biasf)
{
    int i = blockIdx.x * 256 + threadIdx.x;   // 0 .. 2097151
    if (i < 1048576) {              // zf: 8192x1024 / 8
        int lane = i & 63, rest = i >> 6;
        int kk = rest & 1, mfrag = (rest >> 1) & 7, half = (rest >> 4) & 1;
        int kt = (rest >> 5) & 15, mtile = rest >> 9;
        int row = mtile * 256 + half * 128 + mfrag * 16 + (lane & 15);
        int k = kt * 64 + kk * 32 + (lane >> 4) * 8;
        cvt8store(z + (size_t)row * 1024 + k, zf + (size_t)i * 8);
    }
    int i2 = i - 1048576;
    if (i2 >= 0 && i2 < 393216) {   // wqkvf: 3072x1024 / 8
        int lane = i2 & 63, rest = i2 >> 6;
        int kk = rest & 1, nfrag = (rest >> 1) & 7;
        int kt = (rest >> 4) & 15, ntile = rest >> 8;
        int n = ntile * 128 + nfrag * 16 + (lane & 15);
        int k = kt * 64 + kk * 32 + (lane >> 4) * 8;
        const float* W = (n < 1024) ? wq : ((n < 2048) ? wk : wv);
        cvt8store(W + (size_t)(n & 1023) * 1024 + k, wqkvf + (size_t)i2 * 8);
    }
    int i3 = i2 - 393216;
    if (i3 >= 0 && i3 < 131072) {   // wobf: 1024x1024 / 8
        int lane = i3 & 63, rest = i3 >> 6;
        int kk = rest & 1, nfrag = (rest >> 1) & 7;
        int kt = (rest >> 4) & 15, ntile = rest >> 8;
        int n = ntile * 128 + nfrag * 16 + (lane & 15);
        int k = kt * 64 + kk * 32 + (lane >> 4) * 8;
        cvt8store(wo + (size_t)n * 1024 + k, wobf + (size_t)i3 * 8);
    }
    if (i < 1024) {
        biasf[i]        = bq[i];
        biasf[1024 + i] = bk[i];
        biasf[2048 + i] = bv[i];
    }
}

// ---------------------------------------------------------------------------
// Shared GEMM machinery (R10/R11): 256x128 tile, BK=64, 8 waves, 3-buffer
// rotation, counted vmcnt(6), fragment-linear LDS.
// ---------------------------------------------------------------------------
__device__ __forceinline__ void g_stage(const unsigned short* __restrict__ as_,
                                        const unsigned short* __restrict__ bs_,
                                        unsigned short* la, unsigned short* lb,
                                        int wid, int lane)
{
#pragma unroll
    for (int g = 0; g < 4; ++g)
        GLL(as_ + (wid + 8 * g) * 512 + lane * 8, la + (wid + 8 * g) * 512);
#pragma unroll
    for (int g = 0; g < 2; ++g)
        GLL(bs_ + (wid + 8 * g) * 512 + lane * 8, lb + (wid + 8 * g) * 512);
}

#define GEMM_KLOOP(Abase, Bbase)                                                      \
    g_stage(Abase, Bbase, &ldsA[0][0], &ldsB[0][0], wid, lane);                       \
    g_stage(Abase + 16384, Bbase + 8192, &ldsA[1][0], &ldsB[1][0], wid, lane);        \
    asm volatile("s_waitcnt vmcnt(6)" ::: "memory");                                  \
    __builtin_amdgcn_s_barrier();                                                     \
    for (int t = 0; t < 16; ++t) {                                                    \
        int buf = t % 3;                                                              \
        if (t + 2 < 16)                                                               \
            g_stage(Abase + (size_t)(t + 2) * 16384, Bbase + (size_t)(t + 2) * 8192,  \
                    &ldsA[(t + 2) % 3][0], &ldsB[(t + 2) % 3][0], wid, lane);         \
        const unsigned short* A = &ldsA[buf][0];                                      \
        const unsigned short* B = &ldsB[buf][0];                                      \
        bf16x8 b00 = *(const bf16x8*)(B + ((wn * 2 + 0) * 2 + 0) * 512 + lane * 8);   \
        bf16x8 b01 = *(const bf16x8*)(B + ((wn * 2 + 0) * 2 + 1) * 512 + lane * 8);   \
        bf16x8 b10 = *(const bf16x8*)(B + ((wn * 2 + 1) * 2 + 0) * 512 + lane * 8);   \
        bf16x8 b11 = *(const bf16x8*)(B + ((wn * 2 + 1) * 2 + 1) * 512 + lane * 8);   \
        _Pragma("unroll")                                                             \
        for (int ii = 0; ii < 8; ++ii) {                                              \
            bf16x8 a0 = *(const bf16x8*)(A + ((wm * 8 + ii) * 2 + 0) * 512 + lane * 8); \
            bf16x8 a1 = *(const bf16x8*)(A + ((wm * 8 + ii) * 2 + 1) * 512 + lane * 8); \
            acc[ii][0] = __builtin_amdgcn_mfma_f32_16x16x32_bf16(a0, b00, acc[ii][0], 0, 0, 0); \
            acc[ii][0] = __builtin_amdgcn_mfma_f32_16x16x32_bf16(a1, b01, acc[ii][0], 0, 0, 0); \
            acc[ii][1] = __builtin_amdgcn_mfma_f32_16x16x32_bf16(a0, b10, acc[ii][1], 0, 0, 0); \
            acc[ii][1] = __builtin_amdgcn_mfma_f32_16x16x32_bf16(a1, b11, acc[ii][1], 0, 0, 0); \
        }                                                                             \
        if (t < 14)       { asm volatile("s_waitcnt vmcnt(6)" ::: "memory"); }        \
        else if (t == 14) { asm volatile("s_waitcnt vmcnt(0)" ::: "memory"); }        \
        if (t < 15) { __builtin_amdgcn_sched_barrier(0); __builtin_amdgcn_s_barrier(); } \
    }

// ---------------------------------------------------------------------------
// Kernel 2: QKV projection (R11). Q row-major (pre-scaled log2e/8); K/V
// scattered into attention fragment order (V in the x16 A-frag layout).
// ---------------------------------------------------------------------------
__global__ __launch_bounds__(512) void k_gemm_qkv(
    const unsigned short* __restrict__ Af,   // zfrag
    const unsigned short* __restrict__ Bf,   // wqkvfrag
    const float* __restrict__ biasf,
    unsigned short* __restrict__ qb, unsigned short* __restrict__ kfrag,
    unsigned short* __restrict__ vfrag)
{
    __shared__ unsigned short ldsA[3][16384];
    __shared__ unsigned short ldsB[3][8192];

    int bid = blockIdx.x;
    int wg = (bid & 7) * 96 + (bid >> 3);    // 768 blocks, XCD-contiguous
    int tn = wg % 24, tm = wg / 24;
    int tid = threadIdx.x, wid = tid >> 6, lane = tid & 63;
    int wm = wid >> 2, wn = wid & 3;

    const unsigned short* Abase = Af + (size_t)tm * 16 * 16384;
    const unsigned short* Bbase = Bf + (size_t)tn * 16 * 8192;

    f32x4 acc[8][2] = {};
    GEMM_KLOOP(Abase, Bbase)

    const float QSC = 0.18033688011112042f;  // log2(e) / sqrt(64)
    int t3 = tn >> 3;  // 0=Q 1=K 2=V
#pragma unroll
    for (int j = 0; j < 2; ++j) {
        int col = tn * 128 + wn * 32 + j * 16 + (lane & 15);
        float bias = biasf[col];
        int d = col & 1023, h = d >> 6, dk = d & 63;
#pragma unroll
        for (int i = 0; i < 8; ++i) {
#pragma unroll
            for (int r = 0; r < 4; ++r) {
                int row = tm * 256 + wm * 128 + i * 16 + (lane >> 4) * 4 + r;
                float v = acc[i][j][r] + bias;
                if (t3 == 0) v *= QSC;
                unsigned short bv16 = f2bf(v);
                int b_ = row >> 11, s_ = row & 2047;
                int bh = b_ * NHEAD + h;
                if (t3 == 0) {
                    qb[((size_t)bh * SEQ + s_) * DKH + dk] = bv16;
                } else if (t3 == 1) {
                    int kvblk = s_ >> 6, r64 = s_ & 63;
                    int t32 = r64 >> 5, l5 = r64 & 31;
                    int ds = dk >> 4, hi2 = (dk >> 3) & 1, e = dk & 7;
                    kfrag[((size_t)(bh * 32 + kvblk)) * 4096 +
                          (t32 * 4 + ds) * 512 + (hi2 * 32 + l5) * 8 + e] = bv16;
                } else {
                    // V x16 A-frag: elem = V[kv = s*16+hi*8+e][d = vt*32+l5]
                    int kvblk = s_ >> 6, kv64 = s_ & 63;
                    int s16 = kv64 >> 4, hi2 = (kv64 >> 3) & 1, e = kv64 & 7;
                    int vt = dk >> 5, l5 = dk & 31;
                    vfrag[((size_t)(bh * 32 + kvblk)) * 4096 +
                          (vt * 4 + s16) * 512 + (hi2 * 32 + l5) * 8 + e] = bv16;
                }
            }
        }
    }
}

// ---------------------------------------------------------------------------
// Kernel 3: flash attention, barrier-free register streaming (R13 base) +
//   (a) in-place K prefetch: kf registers refilled with tile kt+1 right after
//       the QK^T cluster (WAR dep orders it; issued before vf so the vf-wait
//       doesn't cover it) -> K L2 latency hides under exp/pack/PV.
//   (b) P row-sum via ones-MFMA: psum = mfma(ones, w[s], psum) replaces 32
//       scalar VALU adds per kt (and the epilogue shfl) - moves work from the
//       48%-busy VALU pipe to the 30%-busy MFMA pipe.
// ---------------------------------------------------------------------------
__global__ __launch_bounds__(512) void k_attn(
    const unsigned short* __restrict__ qg,
    const unsigned short* __restrict__ kb,
    const unsigned short* __restrict__ vtb,
    unsigned short* __restrict__ ctxf)
{
    int bid = blockIdx.x;
    // XCD-grouped swizzle: the 8 q-tiles of a (b,h) land on the same XCD.
    int x = bid & 7, li = bid >> 3;
    int bh = x * 8 + (li >> 3);
    int qt = li & 7;

    int tid = threadIdx.x, wid = tid >> 6, lane = tid & 63;
    int lq = lane & 31, hi = lane >> 5;

    // Q B-frags: col q = lane&31, k(d) = ds*16 + hi*8 + e
    bf16x8 aq[4];
    {
        const unsigned short* qp = qg + ((size_t)bh * SEQ + qt * 256 + wid * 32 + lq) * DKH + hi * 8;
#pragma unroll
        for (int d = 0; d < 4; ++d) aq[d] = *(const bf16x8*)(qp + d * 16);
    }

    // all-ones A-fragment (bf16 1.0 = 0x3F80) for the P row-sum MFMA
    bf16x8 onesv;
    {
        int4v ob; ob[0] = ob[1] = ob[2] = ob[3] = 0x3F803F80;
        onesv = __builtin_bit_cast(bf16x8, ob);
    }

    f32x16 oa0 = {};    // O^T d-tile 0: col q = lane&31
    f32x16 oa1 = {};    // O^T d-tile 1 (d += 32)
    f32x16 psum = {};   // every reg = sum_k P[k][q] (ones-MFMA accumulator)

    const unsigned short* kpt = kb  + (size_t)bh * 32 * 4096 + lane * 8;
    const unsigned short* vpt = vtb + (size_t)bh * 32 * 4096 + lane * 8;

    // prologue: K(0) fragments
    bf16x8 kf[8];
#pragma unroll
    for (int f = 0; f < 8; ++f) kf[f] = *(const bf16x8*)(kpt + f * 512);

    for (int kt = 0; kt < 32; ++kt) {
        // ---- S^T = K Q^T : 2 kv-subtiles x 4 d-steps of 32x32x16 ----
        f32x16 st0 = {}, st1 = {};
        __builtin_amdgcn_s_setprio(1);
#pragma unroll
        for (int ds = 0; ds < 4; ++ds) {
            st0 = __builtin_amdgcn_mfma_f32_32x32x16_bf16(kf[ds],     aq[ds], st0, 0, 0, 0);
            st1 = __builtin_amdgcn_mfma_f32_32x32x16_bf16(kf[4 + ds], aq[ds], st1, 0, 0, 0);
        }
        __builtin_amdgcn_s_setprio(0);

        // ---- in-place K prefetch for kt+1 (kf regs dead after QK^T issue) ----
        kpt += 4096;
        if (kt < 31) {
#pragma unroll
            for (int f = 0; f < 8; ++f) kf[f] = *(const bf16x8*)(kpt + f * 512);
        }

        // ---- V fragments for current tile (latency hides under exp/pack) ----
        bf16x8 vf[8];
#pragma unroll
        for (int f = 0; f < 8; ++f) vf[f] = *(const bf16x8*)(vpt + f * 512);
        vpt += 4096;

        // ---- P = 2^(S^T); pack bf16 pairs; permlane into PV B-frags ----
        unsigned int w16[16];
#pragma unroll
        for (int jj = 0; jj < 8; ++jj) {
            float p0 = __builtin_amdgcn_exp2f(st0[2 * jj]);
            float p1 = __builtin_amdgcn_exp2f(st0[2 * jj + 1]);
            w16[jj] = packbf2(p0, p1);
        }
#pragma unroll
        for (int jj = 0; jj < 8; ++jj) {
            float p0 = __builtin_amdgcn_exp2f(st1[2 * jj]);
            float p1 = __builtin_amdgcn_exp2f(st1[2 * jj + 1]);
            w16[8 + jj] = packbf2(p0, p1);
        }
        bf16x8 w[4];
#pragma unroll
        for (int s = 0; s < 4; ++s) {
            int base = (s >> 1) * 8 + (s & 1) * 4;
            int2v r1 = __builtin_amdgcn_permlane32_swap((int)w16[base + 0], (int)w16[base + 2], false, false);
            int2v r2 = __builtin_amdgcn_permlane32_swap((int)w16[base + 1], (int)w16[base + 3], false, false);
            int4v fr; fr[0] = r1[0]; fr[1] = r2[0]; fr[2] = r1[1]; fr[3] = r2[1];
            w[s] = __builtin_bit_cast(bf16x8, fr);
        }

        // ---- O^T += V^T @ P ; psum += 1^T @ P (row-sums on the MFMA pipe) ----
        __builtin_amdgcn_s_setprio(1);
#pragma unroll
        for (int s = 0; s < 4; ++s) {
            oa0  = __builtin_amdgcn_mfma_f32_32x32x16_bf16(vf[s],     w[s], oa0,  0, 0, 0);
            oa1  = __builtin_amdgcn_mfma_f32_32x32x16_bf16(vf[4 + s], w[s], oa1,  0, 0, 0);
            psum = __builtin_amdgcn_mfma_f32_32x32x16_bf16(onesv,     w[s], psum, 0, 0, 0);
        }
        __builtin_amdgcn_s_setprio(0);
    }

    // ---- epilogue: scatter ctx into GEMM-A fragment order ----
    // psum: every reg holds the full 64*32-tile col-sum for this lane's q.
    int b_ = bh >> 4, h = bh & 15;
    float inv = 1.0f / psum[0];
    int s_ = qt * 256 + wid * 32 + lq;
    int row = b_ * 2048 + s_;
    int mtile = row >> 8, half = (row >> 7) & 1, mfrag = (row >> 4) & 7, lrow = row & 15;
    unsigned short* cb = ctxf + (size_t)((mtile * 16 + h) * 2 + half) * 8192
                              + mfrag * 1024 + lrow * 8 + 4 * hi;
#pragma unroll
    for (int m = 0; m < 4; ++m) {
        ushort4v s0, s1;
        s0[0] = f2bf(oa0[4 * m + 0] * inv); s0[1] = f2bf(oa0[4 * m + 1] * inv);
        s0[2] = f2bf(oa0[4 * m + 2] * inv); s0[3] = f2bf(oa0[4 * m + 3] * inv);
        *(ushort4v*)(cb + m * 128) = s0;                 // kk=0 (d<32)
        s1[0] = f2bf(oa1[4 * m + 0] * inv); s1[1] = f2bf(oa1[4 * m + 1] * inv);
        s1[2] = f2bf(oa1[4 * m + 2] * inv); s1[3] = f2bf(oa1[4 * m + 3] * inv);
        *(ushort4v*)(cb + 512 + m * 128) = s1;           // kk=1 (d>=32)
    }
}

// ---------------------------------------------------------------------------
// Kernel 4: output projection (R10/R11)
// ---------------------------------------------------------------------------
__global__ __launch_bounds__(512) void k_gemm_out(
    const unsigned short* __restrict__ Af,   // ctxfrag
    const unsigned short* __restrict__ Bf,   // wobfrag
    const float* __restrict__ bo,
    float* __restrict__ out)
{
    __shared__ unsigned short ldsA[3][16384];
    __shared__ unsigned short ldsB[3][8192];

    int bid = blockIdx.x;
    int wg = (bid & 7) * 32 + (bid >> 3);    // 256 blocks
    int tn = wg % 8, tm = wg / 8;
    int tid = threadIdx.x, wid = tid >> 6, lane = tid & 63;
    int wm = wid >> 2, wn = wid & 3;

    const unsigned short* Abase = Af + (size_t)tm * 16 * 16384;
    const unsigned short* Bbase = Bf + (size_t)tn * 16 * 8192;

    f32x4 acc[8][2] = {};
    GEMM_KLOOP(Abase, Bbase)

#pragma unroll
    for (int j = 0; j < 2; ++j) {
        int col = tn * 128 + wn * 32 + j * 16 + (lane & 15);
        float bias = bo[col];
#pragma unroll
        for (int i = 0; i < 8; ++i) {
#pragma unroll
            for (int r = 0; r < 4; ++r) {
                int row = tm * 256 + wm * 128 + i * 16 + (lane >> 4) * 4 + r;
                out[(size_t)row * 1024 + col] = acc[i][j][r] + bias;
            }
        }
    }
}

// ---------------------------------------------------------------------------
extern "C" void kernel_launch(void* const* d_in, const int* in_sizes, int n_in,
                              void* d_out, int out_size, void* d_ws, size_t ws_size,
                              hipStream_t stream)
{
    const float* z  = (const float*)d_in[0];
    const float* Wq = (const float*)d_in[1];
    const float* bq = (const float*)d_in[2];
    const float* Wk = (const float*)d_in[3];
    const float* bk = (const float*)d_in[4];
    const float* Wv = (const float*)d_in[5];
    const float* bv = (const float*)d_in[6];
    const float* Wo = (const float*)d_in[7];
    const float* bo = (const float*)d_in[8];
    float* out = (float*)d_out;

    char* ws = (char*)d_ws;
    unsigned short* zf    = (unsigned short*)(ws);                        // 16 MB
    unsigned short* ctxf  = (unsigned short*)(ws);                        // 16 MB (reuse)
    unsigned short* wqkvf = (unsigned short*)(ws + (16ull << 20));        //  6 MB
    unsigned short* wobf  = (unsigned short*)(ws + (22ull << 20));        //  2 MB
    float*          biasf = (float*)(ws + (24ull << 20));                 // 12 KB
    unsigned short* qb    = (unsigned short*)(ws + (25ull << 20));        // 16 MB
    unsigned short* kfrag = (unsigned short*)(ws + (41ull << 20));        // 16 MB
    unsigned short* vfrag = (unsigned short*)(ws + (57ull << 20));        // 16 MB -> 73 MB total

    k_convert<<<8192, 256, 0, stream>>>(z, Wq, Wk, Wv, Wo, bq, bk, bv, zf, wqkvf, wobf, biasf);
    k_gemm_qkv<<<768, 512, 0, stream>>>(zf, wqkvf, biasf, qb, kfrag, vfrag);
    k_attn<<<NBH * 8, 512, 0, stream>>>(qb, kfrag, vfrag, ctxf);
    k_gemm_out<<<256, 512, 0, stream>>>(ctxf, wobf, bo, out);
}

// Round 16
// 207.829 us; speedup vs baseline: 1.1130x; 1.0646x over previous
//
#include <hip/hip_runtime.h>
#include <stdint.h>

#define D_MODEL 1024
#define NHEAD 16
#define DKH 64
#define BATCH 4
#define SEQ 2048
#define M_ROWS (BATCH*SEQ)   // 8192
#define NBH (BATCH*NHEAD)    // 64

typedef float f32x4 __attribute__((ext_vector_type(4)));
typedef float f32x16 __attribute__((ext_vector_type(16)));
typedef __bf16 bf16x8 __attribute__((ext_vector_type(8)));
typedef unsigned short ushort4v __attribute__((ext_vector_type(4)));
typedef unsigned short ushort8v __attribute__((ext_vector_type(8)));
typedef int int2v __attribute__((ext_vector_type(2)));
typedef int int4v __attribute__((ext_vector_type(4)));

__device__ __forceinline__ unsigned short f2bf(float x) {
    __bf16 b = (__bf16)x;                      // hardware v_cvt (RNE)
    return __builtin_bit_cast(unsigned short, b);
}
__device__ __forceinline__ unsigned int packbf2(float lo, float hi) {
    return (unsigned int)f2bf(lo) | ((unsigned int)f2bf(hi) << 16);
}

#define GLL(gsrc, ldst) \
    __builtin_amdgcn_global_load_lds((const __attribute__((address_space(1))) void*)(gsrc), \
                                     (__attribute__((address_space(3))) void*)(ldst), 16, 0, 0)

// ---------------------------------------------------------------------------
// Fragment-order layouts (32x32 MFMA GEMM):
//   GEMM A tile (256m x 64k): [mtile][kt][mf32(8)][kk16(4)][lane(64)][e8]
//     row = mtile*256 + mf32*32 + (lane&31); k = kt*64 + kk16*16 + (lane>>5)*8 + e
//     tile = 16384 elems (32KB)
//   GEMM B tile (128n x 64k): [ntile][kt][nf32(4)][kk16(4)][lane][e8]
//     col = ntile*128 + nf32*32 + (lane&31); same k.  tile = 8192 elems (16KB)
//   attn K tile (64kv x 64d): [t32(2)][ds(4)][hi*32+row31][e8]  (unchanged)
//   attn V tile (64kv x 64d): [vt(2)][s(4)][hi*32+d31][e8]      (unchanged)
// ---------------------------------------------------------------------------

__device__ __forceinline__ void cvt8store(const float* __restrict__ src,
                                          unsigned short* __restrict__ dst) {
    float4 v0 = *(const float4*)(src);
    float4 v1 = *(const float4*)(src + 4);
    ushort8v o;
    o[0] = f2bf(v0.x); o[1] = f2bf(v0.y); o[2] = f2bf(v0.z); o[3] = f2bf(v0.w);
    o[4] = f2bf(v1.x); o[5] = f2bf(v1.y); o[6] = f2bf(v1.z); o[7] = f2bf(v1.w);
    *(ushort8v*)dst = o;
}

// ---------------------------------------------------------------------------
// Kernel 1: fp32 -> bf16 fragment-order packing (32x32 frag layouts)
// ---------------------------------------------------------------------------
__global__ __launch_bounds__(256) void k_convert(
    const float* __restrict__ z,  const float* __restrict__ wq,
    const float* __restrict__ wk, const float* __restrict__ wv,
    const float* __restrict__ wo,
    const float* __restrict__ bq, const float* __restrict__ bk,
    const float* __restrict__ bv,
    unsigned short* __restrict__ zf, unsigned short* __restrict__ wqkvf,
    unsigned short* __restrict__ wobf, float* __restrict__ biasf)
{
    int i = blockIdx.x * 256 + threadIdx.x;   // 0 .. 2097151
    if (i < 1048576) {              // zf: 8192x1024 / 8
        int lane = i & 63, rest = i >> 6;
        int kk16 = rest & 3, mf32 = (rest >> 2) & 7;
        int kt = (rest >> 5) & 15, mtile = rest >> 9;
        int row = mtile * 256 + mf32 * 32 + (lane & 31);
        int k = kt * 64 + kk16 * 16 + (lane >> 5) * 8;
        cvt8store(z + (size_t)row * 1024 + k, zf + (size_t)i * 8);
    }
    int i2 = i - 1048576;
    if (i2 >= 0 && i2 < 393216) {   // wqkvf: 3072x1024 / 8
        int lane = i2 & 63, rest = i2 >> 6;
        int kk16 = rest & 3, nf32 = (rest >> 2) & 3;
        int kt = (rest >> 4) & 15, ntile = rest >> 8;
        int n = ntile * 128 + nf32 * 32 + (lane & 31);
        int k = kt * 64 + kk16 * 16 + (lane >> 5) * 8;
        const float* W = (n < 1024) ? wq : ((n < 2048) ? wk : wv);
        cvt8store(W + (size_t)(n & 1023) * 1024 + k, wqkvf + (size_t)i2 * 8);
    }
    int i3 = i2 - 393216;
    if (i3 >= 0 && i3 < 131072) {   // wobf: 1024x1024 / 8
        int lane = i3 & 63, rest = i3 >> 6;
        int kk16 = rest & 3, nf32 = (rest >> 2) & 3;
        int kt = (rest >> 4) & 15, ntile = rest >> 8;
        int n = ntile * 128 + nf32 * 32 + (lane & 31);
        int k = kt * 64 + kk16 * 16 + (lane >> 5) * 8;
        cvt8store(wo + (size_t)n * 1024 + k, wobf + (size_t)i3 * 8);
    }
    if (i < 1024) {
        biasf[i]        = bq[i];
        biasf[1024 + i] = bk[i];
        biasf[2048 + i] = bv[i];
    }
}

// ---------------------------------------------------------------------------
// Shared GEMM machinery: 256x128 tile, BK=64, 8 waves (4m x 2n, 64x64/wave),
// 32x32x16 MFMA (halves LDS bytes/FLOP: 128KB/t vs 160KB/t), 3-buffer
// rotation, counted vmcnt(6), fragment-linear LDS (zero conflicts).
// ---------------------------------------------------------------------------
__device__ __forceinline__ void g_stage(const unsigned short* __restrict__ as_,
                                        const unsigned short* __restrict__ bs_,
                                        unsigned short* la, unsigned short* lb,
                                        int wid, int lane)
{
#pragma unroll
    for (int g = 0; g < 4; ++g)
        GLL(as_ + (wid + 8 * g) * 512 + lane * 8, la + (wid + 8 * g) * 512);
#pragma unroll
    for (int g = 0; g < 2; ++g)
        GLL(bs_ + (wid + 8 * g) * 512 + lane * 8, lb + (wid + 8 * g) * 512);
}

#define GEMM_KLOOP(Abase, Bbase)                                                      \
    g_stage(Abase, Bbase, &ldsA[0][0], &ldsB[0][0], wid, lane);                       \
    g_stage(Abase + 16384, Bbase + 8192, &ldsA[1][0], &ldsB[1][0], wid, lane);        \
    asm volatile("s_waitcnt vmcnt(6)" ::: "memory");                                  \
    __builtin_amdgcn_s_barrier();                                                     \
    for (int t = 0; t < 16; ++t) {                                                    \
        int buf = t % 3;                                                              \
        if (t + 2 < 16)                                                               \
            g_stage(Abase + (size_t)(t + 2) * 16384, Bbase + (size_t)(t + 2) * 8192,  \
                    &ldsA[(t + 2) % 3][0], &ldsB[(t + 2) % 3][0], wid, lane);         \
        const unsigned short* A = &ldsA[buf][0];                                      \
        const unsigned short* B = &ldsB[buf][0];                                      \
        _Pragma("unroll")                                                             \
        for (int kk = 0; kk < 4; ++kk) {                                              \
            bf16x8 a0 = *(const bf16x8*)(A + ((2 * wm + 0) * 4 + kk) * 512 + lane * 8); \
            bf16x8 a1 = *(const bf16x8*)(A + ((2 * wm + 1) * 4 + kk) * 512 + lane * 8); \
            bf16x8 b0 = *(const bf16x8*)(B + ((2 * wn + 0) * 4 + kk) * 512 + lane * 8); \
            bf16x8 b1 = *(const bf16x8*)(B + ((2 * wn + 1) * 4 + kk) * 512 + lane * 8); \
            acc[0][0] = __builtin_amdgcn_mfma_f32_32x32x16_bf16(a0, b0, acc[0][0], 0, 0, 0); \
            acc[0][1] = __builtin_amdgcn_mfma_f32_32x32x16_bf16(a0, b1, acc[0][1], 0, 0, 0); \
            acc[1][0] = __builtin_amdgcn_mfma_f32_32x32x16_bf16(a1, b0, acc[1][0], 0, 0, 0); \
            acc[1][1] = __builtin_amdgcn_mfma_f32_32x32x16_bf16(a1, b1, acc[1][1], 0, 0, 0); \
        }                                                                             \
        if (t < 14)       { asm volatile("s_waitcnt vmcnt(6)" ::: "memory"); }        \
        else if (t == 14) { asm volatile("s_waitcnt vmcnt(0)" ::: "memory"); }        \
        if (t < 15) { __builtin_amdgcn_sched_barrier(0); __builtin_amdgcn_s_barrier(); } \
    }

// ---------------------------------------------------------------------------
// Kernel 2: QKV projection. Q row-major (pre-scaled log2e/8); K/V scattered
// into attention fragment order (unchanged layouts).
// C layout (32x32): col(n) = lane&31, row(m) = (r&3)+8(r>>2)+4(lane>>5).
// ---------------------------------------------------------------------------
__global__ __launch_bounds__(512) void k_gemm_qkv(
    const unsigned short* __restrict__ Af,   // zfrag
    const unsigned short* __restrict__ Bf,   // wqkvfrag
    const float* __restrict__ biasf,
    unsigned short* __restrict__ qb, unsigned short* __restrict__ kfrag,
    unsigned short* __restrict__ vfrag)
{
    __shared__ unsigned short ldsA[3][16384];
    __shared__ unsigned short ldsB[3][8192];

    int bid = blockIdx.x;
    int wg = (bid & 7) * 96 + (bid >> 3);    // 768 blocks, XCD-contiguous
    int tn = wg % 24, tm = wg / 24;
    int tid = threadIdx.x, wid = tid >> 6, lane = tid & 63;
    int wm = wid >> 1, wn = wid & 1;

    const unsigned short* Abase = Af + (size_t)tm * 16 * 16384;
    const unsigned short* Bbase = Bf + (size_t)tn * 16 * 8192;

    f32x16 acc[2][2] = {};
    GEMM_KLOOP(Abase, Bbase)

    const float QSC = 0.18033688011112042f;  // log2(e) / sqrt(64)
    int t3 = tn >> 3;  // 0=Q 1=K 2=V
    int rowc = (lane >> 5) * 4;              // C-row lane component
#pragma unroll
    for (int bn = 0; bn < 2; ++bn) {
        int col = tn * 128 + wn * 64 + bn * 32 + (lane & 31);
        float bias = biasf[col];
        int d = col & 1023, h = d >> 6, dk = d & 63;
#pragma unroll
        for (int am = 0; am < 2; ++am) {
#pragma unroll
            for (int r = 0; r < 16; ++r) {
                int row = tm * 256 + wm * 64 + am * 32 + (r & 3) + 8 * (r >> 2) + rowc;
                float v = acc[am][bn][r] + bias;
                if (t3 == 0) v *= QSC;
                unsigned short bv16 = f2bf(v);
                int b_ = row >> 11, s_ = row & 2047;
                int bh = b_ * NHEAD + h;
                if (t3 == 0) {
                    qb[((size_t)bh * SEQ + s_) * DKH + dk] = bv16;
                } else if (t3 == 1) {
                    int kvblk = s_ >> 6, r64 = s_ & 63;
                    int t32 = r64 >> 5, l5 = r64 & 31;
                    int ds = dk >> 4, hi2 = (dk >> 3) & 1, e = dk & 7;
                    kfrag[((size_t)(bh * 32 + kvblk)) * 4096 +
                          (t32 * 4 + ds) * 512 + (hi2 * 32 + l5) * 8 + e] = bv16;
                } else {
                    // V x16 A-frag: elem = V[kv = s*16+hi*8+e][d = vt*32+l5]
                    int kvblk = s_ >> 6, kv64 = s_ & 63;
                    int s16 = kv64 >> 4, hi2 = (kv64 >> 3) & 1, e = kv64 & 7;
                    int vt = dk >> 5, l5 = dk & 31;
                    vfrag[((size_t)(bh * 32 + kvblk)) * 4096 +
                          (vt * 4 + s16) * 512 + (hi2 * 32 + l5) * 8 + e] = bv16;
                }
            }
        }
    }
}

// ---------------------------------------------------------------------------
// Kernel 3: flash attention, barrier-free register streaming (R13 exact),
// epilogue scatters ctx into the 32x32 GEMM-A fragment order.
// ---------------------------------------------------------------------------
__global__ __launch_bounds__(512) void k_attn(
    const unsigned short* __restrict__ qg,
    const unsigned short* __restrict__ kb,
    const unsigned short* __restrict__ vtb,
    unsigned short* __restrict__ ctxf)
{
    int bid = blockIdx.x;
    // XCD-grouped swizzle: the 8 q-tiles of a (b,h) land on the same XCD.
    int x = bid & 7, li = bid >> 3;
    int bh = x * 8 + (li >> 3);
    int qt = li & 7;

    int tid = threadIdx.x, wid = tid >> 6, lane = tid & 63;
    int lq = lane & 31, hi = lane >> 5;

    // Q B-frags: col q = lane&31, k(d) = ds*16 + hi*8 + e
    bf16x8 aq[4];
    {
        const unsigned short* qp = qg + ((size_t)bh * SEQ + qt * 256 + wid * 32 + lq) * DKH + hi * 8;
#pragma unroll
        for (int d = 0; d < 4; ++d) aq[d] = *(const bf16x8*)(qp + d * 16);
    }

    float lsum = 0.f;
    f32x16 oa0 = {};   // O^T d-tile 0: col q = lane&31, row d = (r&3)+8(r>>2)+4hi
    f32x16 oa1 = {};   // O^T d-tile 1 (d += 32)

    const unsigned short* kp = kb  + (size_t)bh * 32 * 4096 + lane * 8;
    const unsigned short* vp = vtb + (size_t)bh * 32 * 4096 + lane * 8;

    for (int kt = 0; kt < 32; ++kt) {
        // ---- K fragments straight to registers (8x dwordx4, coalesced) ----
        bf16x8 kf[8];
#pragma unroll
        for (int f = 0; f < 8; ++f) kf[f] = *(const bf16x8*)(kp + f * 512);

        // ---- S^T = K Q^T : 2 kv-subtiles x 4 d-steps of 32x32x16 ----
        f32x16 st0 = {}, st1 = {};
        __builtin_amdgcn_s_setprio(1);
#pragma unroll
        for (int ds = 0; ds < 4; ++ds) {
            st0 = __builtin_amdgcn_mfma_f32_32x32x16_bf16(kf[ds],     aq[ds], st0, 0, 0, 0);
            st1 = __builtin_amdgcn_mfma_f32_32x32x16_bf16(kf[4 + ds], aq[ds], st1, 0, 0, 0);
        }
        __builtin_amdgcn_s_setprio(0);

        // ---- V fragments to registers (K regs dead; latency hides under exp) ----
        bf16x8 vf[8];
#pragma unroll
        for (int f = 0; f < 8; ++f) vf[f] = *(const bf16x8*)(vp + f * 512);

        // ---- P = 2^(S^T); pack bf16 pairs; permlane into PV B-frags ----
        unsigned int w16[16];
#pragma unroll
        for (int jj = 0; jj < 8; ++jj) {
            float p0 = __builtin_amdgcn_exp2f(st0[2 * jj]);
            float p1 = __builtin_amdgcn_exp2f(st0[2 * jj + 1]);
            lsum += p0 + p1;
            w16[jj] = packbf2(p0, p1);
        }
#pragma unroll
        for (int jj = 0; jj < 8; ++jj) {
            float p0 = __builtin_amdgcn_exp2f(st1[2 * jj]);
            float p1 = __builtin_amdgcn_exp2f(st1[2 * jj + 1]);
            lsum += p0 + p1;
            w16[8 + jj] = packbf2(p0, p1);
        }
        bf16x8 w[4];
#pragma unroll
        for (int s = 0; s < 4; ++s) {
            int base = (s >> 1) * 8 + (s & 1) * 4;
            int2v r1 = __builtin_amdgcn_permlane32_swap((int)w16[base + 0], (int)w16[base + 2], false, false);
            int2v r2 = __builtin_amdgcn_permlane32_swap((int)w16[base + 1], (int)w16[base + 3], false, false);
            int4v fr; fr[0] = r1[0]; fr[1] = r2[0]; fr[2] = r1[1]; fr[3] = r2[1];
            w[s] = __builtin_bit_cast(bf16x8, fr);
        }

        // ---- O^T += V^T @ P : 2 d-tiles x 4 K=16-steps of 32x32x16 ----
        __builtin_amdgcn_s_setprio(1);
#pragma unroll
        for (int s = 0; s < 4; ++s) {
            oa0 = __builtin_amdgcn_mfma_f32_32x32x16_bf16(vf[s],     w[s], oa0, 0, 0, 0);
            oa1 = __builtin_amdgcn_mfma_f32_32x32x16_bf16(vf[4 + s], w[s], oa1, 0, 0, 0);
        }
        __builtin_amdgcn_s_setprio(0);

        kp += 4096; vp += 4096;
    }

    // ---- epilogue: scatter ctx into 32x32 GEMM-A fragment order ----
    // ctx row = b*2048+s (mf32 = (row>>5)&7, lane-row = lq); k = h*64 + d,
    // d = T*32 + 4hi + (r&3) + 8(r>>2) -> kk16 = 2T + (g>>1), lane-hi = g&1,
    // e = 4hi + (r&3), g = r>>2.
    int b_ = bh >> 4, h = bh & 15;
    lsum += __shfl_xor(lsum, 32);
    float inv = 1.0f / lsum;
    int s_ = qt * 256 + wid * 32 + lq;
    int row = b_ * 2048 + s_;
    int mtile = row >> 8, mf32 = (row >> 5) & 7;
    unsigned short* cb = ctxf + ((size_t)((mtile * 16 + h) * 8 + mf32)) * 2048 + 4 * hi;
#pragma unroll
    for (int g = 0; g < 4; ++g) {
        int off0 = (2 * 0 + (g >> 1)) * 512 + (lq + 32 * (g & 1)) * 8;   // T=0
        int off1 = (2 * 1 + (g >> 1)) * 512 + (lq + 32 * (g & 1)) * 8;   // T=1
        ushort4v s0, s1;
        s0[0] = f2bf(oa0[4 * g + 0] * inv); s0[1] = f2bf(oa0[4 * g + 1] * inv);
        s0[2] = f2bf(oa0[4 * g + 2] * inv); s0[3] = f2bf(oa0[4 * g + 3] * inv);
        *(ushort4v*)(cb + off0) = s0;
        s1[0] = f2bf(oa1[4 * g + 0] * inv); s1[1] = f2bf(oa1[4 * g + 1] * inv);
        s1[2] = f2bf(oa1[4 * g + 2] * inv); s1[3] = f2bf(oa1[4 * g + 3] * inv);
        *(ushort4v*)(cb + off1) = s1;
    }
}

// ---------------------------------------------------------------------------
// Kernel 4: output projection, 32x32 GEMM, fp32 out
// ---------------------------------------------------------------------------
__global__ __launch_bounds__(512) void k_gemm_out(
    const unsigned short* __restrict__ Af,   // ctxfrag
    const unsigned short* __restrict__ Bf,   // wobfrag
    const float* __restrict__ bo,
    float* __restrict__ out)
{
    __shared__ unsigned short ldsA[3][16384];
    __shared__ unsigned short ldsB[3][8192];

    int bid = blockIdx.x;
    int wg = (bid & 7) * 32 + (bid >> 3);    // 256 blocks
    int tn = wg % 8, tm = wg / 8;
    int tid = threadIdx.x, wid = tid >> 6, lane = tid & 63;
    int wm = wid >> 1, wn = wid & 1;

    const unsigned short* Abase = Af + (size_t)tm * 16 * 16384;
    const unsigned short* Bbase = Bf + (size_t)tn * 16 * 8192;

    f32x16 acc[2][2] = {};
    GEMM_KLOOP(Abase, Bbase)

    int rowc = (lane >> 5) * 4;
#pragma unroll
    for (int bn = 0; bn < 2; ++bn) {
        int col = tn * 128 + wn * 64 + bn * 32 + (lane & 31);
        float bias = bo[col];
#pragma unroll
        for (int am = 0; am < 2; ++am) {
#pragma unroll
            for (int r = 0; r < 16; ++r) {
                int row = tm * 256 + wm * 64 + am * 32 + (r & 3) + 8 * (r >> 2) + rowc;
                out[(size_t)row * 1024 + col] = acc[am][bn][r] + bias;
            }
        }
    }
}

// ---------------------------------------------------------------------------
extern "C" void kernel_launch(void* const* d_in, const int* in_sizes, int n_in,
                              void* d_out, int out_size, void* d_ws, size_t ws_size,
                              hipStream_t stream)
{
    const float* z  = (const float*)d_in[0];
    const float* Wq = (const float*)d_in[1];
    const float* bq = (const float*)d_in[2];
    const float* Wk = (const float*)d_in[3];
    const float* bk = (const float*)d_in[4];
    const float* Wv = (const float*)d_in[5];
    const float* bv = (const float*)d_in[6];
    const float* Wo = (const float*)d_in[7];
    const float* bo = (const float*)d_in[8];
    float* out = (float*)d_out;

    char* ws = (char*)d_ws;
    unsigned short* zf    = (unsigned short*)(ws);                        // 16 MB
    unsigned short* ctxf  = (unsigned short*)(ws);                        // 16 MB (reuse)
    unsigned short* wqkvf = (unsigned short*)(ws + (16ull << 20));        //  6 MB
    unsigned short* wobf  = (unsigned short*)(ws + (22ull << 20));        //  2 MB
    float*          biasf = (float*)(ws + (24ull << 20));                 // 12 KB
    unsigned short* qb    = (unsigned short*)(ws + (25ull << 20));        // 16 MB
    unsigned short* kfrag = (unsigned short*)(ws + (41ull << 20));        // 16 MB
    unsigned short* vfrag = (unsigned short*)(ws + (57ull << 20));        // 16 MB -> 73 MB total

    k_convert<<<8192, 256, 0, stream>>>(z, Wq, Wk, Wv, Wo, bq, bk, bv, zf, wqkvf, wobf, biasf);
    k_gemm_qkv<<<768, 512, 0, stream>>>(zf, wqkvf, biasf, qb, kfrag, vfrag);
    k_attn<<<NBH * 8, 512, 0, stream>>>(qb, kfrag, vfrag, ctxf);
    k_gemm_out<<<256, 512, 0, stream>>>(ctxf, wobf, bo, out);
}